// Round 2
// baseline (1375.614 us; speedup 1.0000x reference)
//
#include <hip/hip_runtime.h>

constexpr int B_ = 16, CIN = 64, COUT = 64, G = 8, CPG = 8;
constexpr int H = 130, W = 130, HO = 128, WO = 128;
constexpr int OFFC = 144;               // G*2*3*3
constexpr int PLANE_IN = H * W;         // 16900
constexpr int PLANE_OUT = HO * WO;      // 16384

// ws float layout (all fp32)
constexpr int WS_W1T = 0;          // 36864  w1t[ci*576 + co*9 + k] = w1[co][ci][k]
constexpr int WS_B1  = 36864;      // 64
constexpr int WS_WDT = 36928;      // 36864  wdt[(cin*9+t)*64 + co] = wd[co][cin][t]
constexpr int WS_TOTAL = 73792;

// K0: transpose weights so conv inner loops read contiguous *uniform*
// (scalar-loadable) weight runs. w2/b2 are already laid out right.
__global__ void transpose_weights(const float* __restrict__ w1,
                                  const float* __restrict__ b1,
                                  const float* __restrict__ wd,
                                  float* __restrict__ ws) {
    int idx = blockIdx.x * 256 + threadIdx.x;
    if (idx < 36864) {                       // w1t[(ci*64+co)*9+k] = w1[co][ci][k]
        int k = idx % 9, q = idx / 9;
        int co = q % 64, ci = q / 64;
        ws[WS_W1T + idx] = w1[(co * 64 + ci) * 9 + k];
    } else if (idx < 36928) {
        ws[idx] = b1[idx - 36864];
    } else if (idx < WS_TOTAL) {             // wdt[(cin*9+t)*64+co] = wd[co][cin][t]
        int j = idx - 36928;
        int co = j % 64, q = j / 64;
        int t = q % 9, cin = q / 9;
        ws[idx] = wd[(co * 64 + cin) * 9 + t];
    }
}

// K1: fused conv1 (3x3 VALID, 64->64) + conv2 (1x1, 64->144).
// One block = 16x16 output tile; x tile staged in LDS in two 32-ci halves.
__global__ __launch_bounds__(256) void conv12(const float* __restrict__ x,
                                              const float* __restrict__ w2,
                                              const float* __restrict__ b2,
                                              const float* __restrict__ ws,
                                              float* __restrict__ off_out) {
    __shared__ float xs[32 * 324];           // 41472 B: 32 ci x (18x18) tile
    const int b = blockIdx.z;
    const int y0 = blockIdx.y * 16, x0 = blockIdx.x * 16;
    const float* xb = x + (size_t)b * CIN * PLANE_IN;
    const int r = threadIdx.x >> 4, c = threadIdx.x & 15;

    float h[64];
    #pragma unroll
    for (int co = 0; co < 64; ++co) h[co] = ws[WS_B1 + co];

    #pragma unroll 1
    for (int half = 0; half < 2; ++half) {
        if (half) __syncthreads();           // prior compute done before overwrite
        for (int t = threadIdx.x; t < 32 * 324; t += 256) {
            int ci = t / 324, p = t % 324;
            int rr = p / 18, cc = p % 18;
            xs[t] = xb[(size_t)(half * 32 + ci) * PLANE_IN + (y0 + rr) * W + (x0 + cc)];
        }
        __syncthreads();
        #pragma unroll 1
        for (int ci = 0; ci < 32; ++ci) {
            float xv[9];
            #pragma unroll
            for (int i = 0; i < 3; ++i)
                #pragma unroll
                for (int j = 0; j < 3; ++j)
                    xv[i * 3 + j] = xs[ci * 324 + (r + i) * 18 + (c + j)];
            const float* wp = ws + WS_W1T + (half * 32 + ci) * 576;   // uniform
            #pragma unroll
            for (int co = 0; co < 64; ++co) {
                float a = h[co];
                #pragma unroll
                for (int k = 0; k < 9; ++k) a = fmaf(xv[k], wp[co * 9 + k], a);
                h[co] = a;
            }
        }
    }

    // conv2: dynamic oc loop, ci fully unrolled so h[ci] is static-indexed.
    float* offp = off_out + (size_t)b * OFFC * PLANE_OUT + (y0 + r) * WO + (x0 + c);
    #pragma unroll 1
    for (int oc = 0; oc < OFFC; ++oc) {
        float a = b2[oc];
        const float* wp = w2 + oc * 64;      // uniform, contiguous 64 floats
        #pragma unroll
        for (int ci = 0; ci < 64; ++ci) a = fmaf(h[ci], wp[ci], a);
        offp[(size_t)oc * PLANE_OUT] = a;
    }
}

// K2: deformable conv. Reads off (fp32) back from d_out, writes y (fp32).
__global__ __launch_bounds__(256) void deform_k(const float* __restrict__ x,
                                                const float* __restrict__ ws,
                                                const float* __restrict__ off_in,
                                                float* __restrict__ y_out) {
    const int b = blockIdx.z;
    const int r = threadIdx.x >> 4, c = threadIdx.x & 15;
    const int ho = blockIdx.y * 16 + r, wo = blockIdx.x * 16 + c;
    const float* xb = x + (size_t)b * CIN * PLANE_IN;
    const float* offb = off_in + (size_t)b * OFFC * PLANE_OUT + ho * WO + wo;

    float acc[64];
    #pragma unroll
    for (int i = 0; i < 64; ++i) acc[i] = 0.f;

    #pragma unroll 1
    for (int g = 0; g < 8; ++g) {
        #pragma unroll 1
        for (int t = 0; t < 9; ++t) {
            const int ki = t / 3, kj = t % 3;
            float dy = offb[(size_t)((g * 9 + t) * 2 + 0) * PLANE_OUT];
            float dx = offb[(size_t)((g * 9 + t) * 2 + 1) * PLANE_OUT];
            float py = dy + (float)(ho + ki);
            float px = dx + (float)(wo + kj);
            float y0f = floorf(py), x0f = floorf(px);
            float ly = py - y0f, lx = px - x0f;
            int yi0 = (int)y0f, xi0 = (int)x0f;
            int yi1 = yi0 + 1, xi1 = xi0 + 1;
            float vy0 = (yi0 >= 0 && yi0 < H) ? 1.f : 0.f;
            float vy1 = (yi1 >= 0 && yi1 < H) ? 1.f : 0.f;
            float vx0 = (xi0 >= 0 && xi0 < W) ? 1.f : 0.f;
            float vx1 = (xi1 >= 0 && xi1 < W) ? 1.f : 0.f;
            float w00 = (1.f - ly) * (1.f - lx) * vy0 * vx0;
            float w01 = (1.f - ly) * lx         * vy0 * vx1;
            float w10 = ly * (1.f - lx)         * vy1 * vx0;
            float w11 = ly * lx                 * vy1 * vx1;
            int yc0 = min(max(yi0, 0), H - 1), yc1 = min(max(yi1, 0), H - 1);
            int xc0 = min(max(xi0, 0), W - 1), xc1 = min(max(xi1, 0), W - 1);
            int i00 = yc0 * W + xc0, i01 = yc0 * W + xc1;
            int i10 = yc1 * W + xc0, i11 = yc1 * W + xc1;
            const float* xg = xb + (size_t)g * CPG * PLANE_IN;
            #pragma unroll 1
            for (int cc = 0; cc < 8; ++cc) {
                const float* xp = xg + cc * PLANE_IN;
                float v = w00 * xp[i00] + w01 * xp[i01]
                        + w10 * xp[i10] + w11 * xp[i11];
                const float* wp = ws + WS_WDT + ((g * 8 + cc) * 9 + t) * 64;  // uniform
                #pragma unroll
                for (int co = 0; co < 64; ++co) acc[co] = fmaf(v, wp[co], acc[co]);
            }
        }
    }

    float* yp = y_out + (size_t)b * COUT * PLANE_OUT + ho * WO + wo;
    #pragma unroll
    for (int co = 0; co < 64; ++co) yp[(size_t)co * PLANE_OUT] = acc[co];
}

extern "C" void kernel_launch(void* const* d_in, const int* in_sizes, int n_in,
                              void* d_out, int out_size, void* d_ws, size_t ws_size,
                              hipStream_t stream) {
    const float* x  = (const float*)d_in[0];
    const float* w1 = (const float*)d_in[1];
    const float* b1 = (const float*)d_in[2];
    const float* w2 = (const float*)d_in[3];
    const float* b2 = (const float*)d_in[4];
    const float* wd = (const float*)d_in[5];
    float* y_out = (float*)d_out;
    float* off_out = y_out + (size_t)B_ * COUT * PLANE_OUT;   // (y, off) concat
    float* ws = (float*)d_ws;

    transpose_weights<<<(WS_TOTAL + 255) / 256, 256, 0, stream>>>(w1, b1, wd, ws);
    conv12<<<dim3(8, 8, B_), 256, 0, stream>>>(x, w2, b2, ws, off_out);
    deform_k<<<dim3(8, 8, B_), 256, 0, stream>>>(x, ws, off_out, y_out);
}

// Round 3
// 646.821 us; speedup vs baseline: 2.1267x; 2.1267x over previous
//
#include <hip/hip_runtime.h>

typedef unsigned short u16;
typedef unsigned int u32;
typedef __attribute__((ext_vector_type(8))) short bfrag;   // 8 x bf16 (4 VGPRs)
typedef __attribute__((ext_vector_type(4))) float ffrag;   // 4 x f32

constexpr int B_ = 16, CIN = 64, COUT = 64, G = 8, CPG = 8;
constexpr int H = 130, W = 130, HO = 128, WO = 128;
constexpr int OFFC = 144;               // G*2*3*3
constexpr int PLANE_IN = H * W;         // 16900
constexpr int PLANE_OUT = HO * WO;      // 16384

// ws layout:
//   float wdt[36864]            : wdt[(cin*9+t)*64+co] = wd[co][cin][t]   (fp32, deform)
//   u16   wB1[64*576] @147456B  : wB1[co*576 + t*64 + ci] = bf16(w1[co][ci][t])
//   u16   wB2[144*64] @221184B  : wB2[oc*64 + ci]         = bf16(w2[oc][ci])
constexpr size_t WB1_BYTE = 36864 * 4;
constexpr size_t WB2_BYTE = WB1_BYTE + 36864 * 2;

__device__ __forceinline__ u16 f2bf(float f) {
    union { u32 u; float f; } t; t.f = f;
    return (u16)((t.u + 0x7FFFu + ((t.u >> 16) & 1u)) >> 16);  // RNE
}

// K0: weight prep (transpose + bf16 conversion).
__global__ void prep_weights(const float* __restrict__ w1,
                             const float* __restrict__ wd,
                             const float* __restrict__ w2,
                             float* __restrict__ wsf) {
    u16* wB1 = (u16*)((char*)wsf + WB1_BYTE);
    u16* wB2 = (u16*)((char*)wsf + WB2_BYTE);
    int idx = blockIdx.x * 256 + threadIdx.x;
    if (idx < 36864) {                        // wdt[(cin*9+t)*64+co]
        int co = idx & 63, q = idx >> 6;
        int t = q % 9, cin = q / 9;
        wsf[idx] = wd[(co * 64 + cin) * 9 + t];
    } else if (idx < 73728) {                 // wB1[co*576 + t*64 + ci]
        int j = idx - 36864;
        int co = j / 576, r = j % 576;
        int t = r >> 6, ci = r & 63;
        wB1[j] = f2bf(w1[(co * 64 + ci) * 9 + t]);
    } else if (idx < 82944) {                 // wB2[oc*64+ci]
        int j = idx - 73728;
        wB2[j] = f2bf(w2[j]);
    }
}

union ConvSmem {
    u16 xs[324 * 72];       // 46656 B : halo tile, xs[p*72 + ci] (row pad 72 -> 2-way banks)
    u16 hs[4][64][72];      // per-wave h buffer [pix][ci], pad 72
};

// K1: fused conv1 (3x3 VALID, 64->64) + conv2 (1x1, 64->144) via bf16 MFMA.
// Block = 16x16 pixel tile, 4 waves; wave w owns rows w*4..w*4+3.
// GEMM1: M=16 pixels/tile (m-tile = spatial row), N=64, K=576 (k = tap*64 + ci).
__global__ __launch_bounds__(256) void conv12(const float* __restrict__ x,
                                              const float* __restrict__ b1,
                                              const float* __restrict__ b2,
                                              const float* __restrict__ wsf,
                                              float* __restrict__ off_out) {
    __shared__ ConvSmem sm;
    const u16* wB1 = (const u16*)((const char*)wsf + WB1_BYTE);
    const u16* wB2 = (const u16*)((const char*)wsf + WB2_BYTE);
    const int b = blockIdx.z;
    const int y0 = blockIdx.y * 16, x0 = blockIdx.x * 16;
    const int tid = threadIdx.x;
    const int wave = tid >> 6, lane = tid & 63;
    const int n16 = lane & 15, quad = lane >> 4;
    const float* xb = x + (size_t)b * CIN * PLANE_IN;

    // stage x tile (18x18 halo x 64 ci) -> LDS bf16, layout [p][ci]
    for (int idx = tid; idx < 324 * 64; idx += 256) {
        int ci = idx / 324, p = idx % 324;            // global-coalesced in p
        float v = xb[(size_t)ci * PLANE_IN + (y0 + p / 18) * W + (x0 + p % 18)];
        sm.xs[p * 72 + ci] = f2bf(v);
    }
    __syncthreads();

    // conv1: acc[mt][nt]; D lane mapping: m=quad*4+reg, n=lane&15
    ffrag acc[4][4];
    #pragma unroll
    for (int nt = 0; nt < 4; ++nt) {
        float bv = b1[nt * 16 + n16];
        #pragma unroll
        for (int mt = 0; mt < 4; ++mt) acc[mt][nt] = ffrag{bv, bv, bv, bv};
    }

    #pragma unroll
    for (int s = 0; s < 18; ++s) {                    // K=576 in 18 slices of 32
        const int tap = s >> 1, cib = (s & 1) * 32;
        const int ti = tap / 3, tj = tap % 3;
        bfrag a[4], bb[4];
        #pragma unroll
        for (int mt = 0; mt < 4; ++mt) {              // A[m=lane&15][k=quad*8+j]
            int p = (wave * 4 + mt + ti) * 18 + n16 + tj;
            a[mt] = *(const bfrag*)&sm.xs[p * 72 + cib + quad * 8];
        }
        #pragma unroll
        for (int nt = 0; nt < 4; ++nt)                // B[n=lane&15][k=quad*8+j]
            bb[nt] = *(const bfrag*)&wB1[(nt * 16 + n16) * 576 + tap * 64 + cib + quad * 8];
        #pragma unroll
        for (int mt = 0; mt < 4; ++mt)
            #pragma unroll
            for (int nt = 0; nt < 4; ++nt)
                acc[mt][nt] = __builtin_amdgcn_mfma_f32_16x16x32_bf16(
                    a[mt], bb[nt], acc[mt][nt], 0, 0, 0);
    }

    __syncthreads();   // all waves done reading xs; reuse as hs

    // D-layout h -> LDS bf16 [pix][ci]; pix = mt*16 + (quad*4+reg), ci = nt*16+n16
    #pragma unroll
    for (int mt = 0; mt < 4; ++mt)
        #pragma unroll
        for (int nt = 0; nt < 4; ++nt)
            #pragma unroll
            for (int r = 0; r < 4; ++r)
                sm.hs[wave][mt * 16 + quad * 4 + r][nt * 16 + n16] = f2bf(acc[mt][nt][r]);
    __syncthreads();   // cheap & definitely safe (cross-lane LDS RAW)

    // conv2 A-frags: A2[m=lane&15][k=quad*8+j], k=ci
    bfrag a2[4][2];
    #pragma unroll
    for (int mt = 0; mt < 4; ++mt)
        #pragma unroll
        for (int s2 = 0; s2 < 2; ++s2)
            a2[mt][s2] = *(const bfrag*)&sm.hs[wave][mt * 16 + n16][s2 * 32 + quad * 8];

    float* offb = off_out + (size_t)b * OFFC * PLANE_OUT;
    #pragma unroll 1
    for (int nt2 = 0; nt2 < 9; ++nt2) {               // N2=144 in 9 n-tiles
        bfrag b2f[2];
        #pragma unroll
        for (int s2 = 0; s2 < 2; ++s2)
            b2f[s2] = *(const bfrag*)&wB2[(nt2 * 16 + n16) * 64 + s2 * 32 + quad * 8];
        float bv = b2[nt2 * 16 + n16];
        #pragma unroll
        for (int mt = 0; mt < 4; ++mt) {
            ffrag acc2 = ffrag{bv, bv, bv, bv};
            acc2 = __builtin_amdgcn_mfma_f32_16x16x32_bf16(a2[mt][0], b2f[0], acc2, 0, 0, 0);
            acc2 = __builtin_amdgcn_mfma_f32_16x16x32_bf16(a2[mt][1], b2f[1], acc2, 0, 0, 0);
            // oc = nt2*16+n16; row = y0+wave*4+mt; cols x0+quad*4 .. +3 -> float4 store
            float* dst = offb + (size_t)(nt2 * 16 + n16) * PLANE_OUT
                       + (y0 + wave * 4 + mt) * WO + x0 + quad * 4;
            *(ffrag*)dst = acc2;
        }
    }
}

// K2: deformable conv (unchanged from R2; wdt now at ws offset 0).
__global__ __launch_bounds__(256) void deform_k(const float* __restrict__ x,
                                                const float* __restrict__ wsf,
                                                const float* __restrict__ off_in,
                                                float* __restrict__ y_out) {
    const int b = blockIdx.z;
    const int r = threadIdx.x >> 4, c = threadIdx.x & 15;
    const int ho = blockIdx.y * 16 + r, wo = blockIdx.x * 16 + c;
    const float* xb = x + (size_t)b * CIN * PLANE_IN;
    const float* offb = off_in + (size_t)b * OFFC * PLANE_OUT + ho * WO + wo;

    float acc[64];
    #pragma unroll
    for (int i = 0; i < 64; ++i) acc[i] = 0.f;

    #pragma unroll 1
    for (int g = 0; g < 8; ++g) {
        #pragma unroll 1
        for (int t = 0; t < 9; ++t) {
            const int ki = t / 3, kj = t % 3;
            float dy = offb[(size_t)((g * 9 + t) * 2 + 0) * PLANE_OUT];
            float dx = offb[(size_t)((g * 9 + t) * 2 + 1) * PLANE_OUT];
            float py = dy + (float)(ho + ki);
            float px = dx + (float)(wo + kj);
            float y0f = floorf(py), x0f = floorf(px);
            float ly = py - y0f, lx = px - x0f;
            int yi0 = (int)y0f, xi0 = (int)x0f;
            int yi1 = yi0 + 1, xi1 = xi0 + 1;
            float vy0 = (yi0 >= 0 && yi0 < H) ? 1.f : 0.f;
            float vy1 = (yi1 >= 0 && yi1 < H) ? 1.f : 0.f;
            float vx0 = (xi0 >= 0 && xi0 < W) ? 1.f : 0.f;
            float vx1 = (xi1 >= 0 && xi1 < W) ? 1.f : 0.f;
            float w00 = (1.f - ly) * (1.f - lx) * vy0 * vx0;
            float w01 = (1.f - ly) * lx         * vy0 * vx1;
            float w10 = ly * (1.f - lx)         * vy1 * vx0;
            float w11 = ly * lx                 * vy1 * vx1;
            int yc0 = min(max(yi0, 0), H - 1), yc1 = min(max(yi1, 0), H - 1);
            int xc0 = min(max(xi0, 0), W - 1), xc1 = min(max(xi1, 0), W - 1);
            int i00 = yc0 * W + xc0, i01 = yc0 * W + xc1;
            int i10 = yc1 * W + xc0, i11 = yc1 * W + xc1;
            const float* xg = xb + (size_t)g * CPG * PLANE_IN;
            #pragma unroll 1
            for (int cc = 0; cc < 8; ++cc) {
                const float* xp = xg + cc * PLANE_IN;
                float v = w00 * xp[i00] + w01 * xp[i01]
                        + w10 * xp[i10] + w11 * xp[i11];
                const float* wp = wsf + ((g * 8 + cc) * 9 + t) * 64;   // uniform
                #pragma unroll
                for (int co = 0; co < 64; ++co) acc[co] = fmaf(v, wp[co], acc[co]);
            }
        }
    }

    float* yp = y_out + (size_t)b * COUT * PLANE_OUT + ho * WO + wo;
    #pragma unroll
    for (int co = 0; co < 64; ++co) yp[(size_t)co * PLANE_OUT] = acc[co];
}

extern "C" void kernel_launch(void* const* d_in, const int* in_sizes, int n_in,
                              void* d_out, int out_size, void* d_ws, size_t ws_size,
                              hipStream_t stream) {
    const float* x  = (const float*)d_in[0];
    const float* w1 = (const float*)d_in[1];
    const float* b1 = (const float*)d_in[2];
    const float* w2 = (const float*)d_in[3];
    const float* b2 = (const float*)d_in[4];
    const float* wd = (const float*)d_in[5];
    float* y_out = (float*)d_out;
    float* off_out = y_out + (size_t)B_ * COUT * PLANE_OUT;   // (y, off) concat
    float* wsf = (float*)d_ws;

    prep_weights<<<324, 256, 0, stream>>>(w1, wd, w2, wsf);
    conv12<<<dim3(8, 8, B_), 256, 0, stream>>>(x, b1, b2, wsf, off_out);
    deform_k<<<dim3(8, 8, B_), 256, 0, stream>>>(x, wsf, off_out, y_out);
}